// Round 9
// baseline (266.092 us; speedup 1.0000x reference)
//
#include <hip/hip_runtime.h>
#include <math.h>

// Problem constants
#define B_  8
#define S_  1024
#define D_  1024
#define H_  16
#define HD_ 64

typedef float          floatx4  __attribute__((ext_vector_type(4)));
typedef __bf16         bf16x8   __attribute__((ext_vector_type(8)));
typedef unsigned int   uintx2   __attribute__((ext_vector_type(2)));
typedef unsigned int   uintx4   __attribute__((ext_vector_type(4)));

__device__ __forceinline__ unsigned short f2bf(float f) {
    union { float f; unsigned u; } v; v.f = f;
    unsigned r = v.u + 0x7FFFu + ((v.u >> 16) & 1u);   // RNE
    return (unsigned short)(r >> 16);
}
__device__ __forceinline__ unsigned pk2(float a, float b) {
    union { __bf16 h[2]; unsigned u; } r;
    r.h[0] = (__bf16)a; r.h[1] = (__bf16)b;
    return r.u;
}
// async global->LDS, 16B per lane; LDS dest = wave-uniform base + lane*16
__device__ __forceinline__ void async16(const void* g, void* l) {
    __builtin_amdgcn_global_load_lds(
        (__attribute__((address_space(1))) void*)g,
        (__attribute__((address_space(3))) void*)l, 16, 0, 0);
}

// ---------------- prep: input casts + all weight transposes, one dispatch ----------
// v2 cast path: 8 floats/array/thread -> 2x floatx4 loads + ONE uintx4 (16B)
// store per array. Halves instruction count vs the 8B-store version (measured
// 2.96 TB/s on 96MB = 32.4us; pure-stream ceiling ~6.3 TB/s).
__global__ __launch_bounds__(256) void prep_k(const float* __restrict__ query,
                                              const float* __restrict__ value,
                                              unsigned short* __restrict__ qbf,
                                              unsigned short* __restrict__ vbf,
                                              const float* __restrict__ Wq,
                                              const float* __restrict__ Wkv,
                                              const float* __restrict__ Wo,
                                              unsigned short* __restrict__ WqT,
                                              unsigned short* __restrict__ WkvT,
                                              unsigned short* __restrict__ WoT) {
    __shared__ float T[64 * 68];
    const int t   = threadIdx.x;
    const int bid = blockIdx.x;
    if (bid < 4096) {
        int i = bid * 256 + t;                    // [0, 1048576): 8 floats each
        const floatx4* qf = (const floatx4*)query;
        const floatx4* vf = (const floatx4*)value;
        floatx4 a0 = qf[2 * i], a1 = qf[2 * i + 1];
        floatx4 b0 = vf[2 * i], b1 = vf[2 * i + 1];
        uintx4 oa = { pk2(a0[0], a0[1]), pk2(a0[2], a0[3]),
                      pk2(a1[0], a1[1]), pk2(a1[2], a1[3]) };
        uintx4 ob = { pk2(b0[0], b0[1]), pk2(b0[2], b0[3]),
                      pk2(b1[0], b1[1]), pk2(b1[2], b1[3]) };
        ((uintx4*)qbf)[i] = oa;
        ((uintx4*)vbf)[i] = ob;
        return;
    }
    const int lin = bid - 4096;                   // [0,1024): weight transposes
    const int z   = lin >> 8;
    const float* W; unsigned short* WT; int Ndim, nbase;
    if (z == 0)      { W = Wq;  WT = WqT;  Ndim = 1024; nbase = 0; }
    else if (z == 3) { W = Wo;  WT = WoT;  Ndim = 1024; nbase = 0; }
    else             { W = Wkv; WT = WkvT; Ndim = 2048; nbase = (z - 1) * 1024; }
    const int n0 = (lin & 15) * 64 + nbase;
    const int k0 = ((lin >> 4) & 15) * 64;
#pragma unroll
    for (int rep = 0; rep < 4; ++rep) {
        int kl = (t >> 4) + rep * 16;
        int ns = (t & 15) * 4;
        *(floatx4*)(T + kl * 68 + ns) = *(const floatx4*)(W + (size_t)(k0 + kl) * Ndim + n0 + ns);
    }
    __syncthreads();
#pragma unroll
    for (int rep = 0; rep < 2; ++rep) {
        int nl = (t >> 3) + rep * 32;
        int ks = (t & 7) * 8;
        union { unsigned short s[8]; uintx4 u; } o;
#pragma unroll
        for (int j = 0; j < 8; ++j) o.s[j] = f2bf(T[(ks + j) * 68 + nl]);
        *(uintx4*)(WT + (size_t)(n0 + nl) * 1024 + k0 + ks) = o.u;
    }
}

// ---------------- shared GEMM K-loop: BK=64, XOR-swizzled LDS (verified) ----------
// LDS tile rows: 64 shorts (128 B = one full bank sweep), logical 8-short chunk c
// of row r stored at position c^(r&7); inverse swizzle applied on global source.
// Fragment reads then alias only 2-way (free). SWAP=1 -> D^T (row=n,col=m).
// ga0/gb0 must already include (+ lrow*1024 + lswz).
template<int SWAP>
__device__ __forceinline__ void kloop(const unsigned short* __restrict__ ga0,
                                      const unsigned short* __restrict__ gb0,
                                      unsigned short* __restrict__ As,
                                      unsigned short* __restrict__ Bs,
                                      floatx4 (&acc)[4][4],
                                      int w, int lane) {
    const int quad = lane >> 4;
    const int l15  = lane & 15;
    const int e7   = l15 & 7;
    const int wr   = (w >> 1) * 64;
    const int wc   = (w & 1) * 64;
    for (int k0 = 0; k0 < 1024; k0 += 64) {
        if (k0) __syncthreads();   // prev-iter LDS reads done before overwrite
#pragma unroll
        for (int i = 0; i < 4; ++i) {
            int c = i * 4 + w;     // rows [c*8, c*8+8)
            async16(ga0 + (size_t)(c * 8) * 1024 + k0, As + c * 512);
            async16(gb0 + (size_t)(c * 8) * 1024 + k0, Bs + c * 512);
        }
        __syncthreads();           // drains vmcnt before fragment reads
#pragma unroll
        for (int ks = 0; ks < 2; ++ks) {
            bf16x8 af[4], bf[4];
#pragma unroll
            for (int mi = 0; mi < 4; ++mi)
                af[mi] = *(const bf16x8*)(As + (wr + mi * 16 + l15) * 64 + (((ks * 4 + quad) ^ e7) * 8));
#pragma unroll
            for (int ni = 0; ni < 4; ++ni)
                bf[ni] = *(const bf16x8*)(Bs + (wc + ni * 16 + l15) * 64 + (((ks * 4 + quad) ^ e7) * 8));
#pragma unroll
            for (int mi = 0; mi < 4; ++mi)
#pragma unroll
                for (int ni = 0; ni < 4; ++ni)
                    acc[mi][ni] = SWAP
                        ? __builtin_amdgcn_mfma_f32_16x16x32_bf16(bf[ni], af[mi], acc[mi][ni], 0, 0, 0)
                        : __builtin_amdgcn_mfma_f32_16x16x32_bf16(af[mi], bf[ni], acc[mi][ni], 0, 0, 0);
        }
    }
}

// ---------------- fused Q + KV projection GEMM (round-4 measured best: 62-63.5us) -
// blocks [0,512):    Q:  Qb[m][n]  = (qbf*WqT + bq) * cexp
// blocks [512,1536): KV: n0<1024 -> Kb[m][n]; n0>=1024 -> V: transposed
//                    packed write Vtg[(b*1024+c)][s]
// Epilogue bounces C through the dead staging LDS (16B/lane coalesced stores).
__global__ __launch_bounds__(256, 4) void qkv_gemm_k(const unsigned short* __restrict__ qbf,
                                                     const unsigned short* __restrict__ vbf,
                                                     const unsigned short* __restrict__ WqT,
                                                     const unsigned short* __restrict__ WkvT,
                                                     const float* __restrict__ bq,
                                                     const float* __restrict__ bkv,
                                                     unsigned short* __restrict__ Qb,
                                                     unsigned short* __restrict__ Kb,
                                                     unsigned short* __restrict__ Vtg,
                                                     float cexp) {
    __shared__ unsigned short SMEM[2 * 128 * 64];   // As | Bs; reused by epilogue
    unsigned short* As = SMEM;
    unsigned short* Bs = SMEM + 128 * 64;
    const int t    = threadIdx.x;
    const int lane = t & 63;
    const int w    = t >> 6;
    const int quad = lane >> 4;
    const int l15  = lane & 15;
    const int wr   = (w >> 1) * 64;
    const int wc   = (w & 1) * 64;
    const int lrow = lane >> 3;
    const int lswz = ((lane & 7) ^ lrow) * 8;

    const int bid = blockIdx.x;
    int m0, n0;
    const unsigned short *Ap, *Wp;
    const float* bp;
    unsigned short* outp;
    float sc;
    bool vpath = false;
    if (bid < 512) {
        m0 = (bid & 63) * 128; n0 = (bid >> 6) * 128;
        Ap = qbf; Wp = WqT; bp = bq; outp = Qb; sc = cexp;
    } else {
        int b2 = bid - 512;
        m0 = (b2 & 63) * 128; n0 = (b2 >> 6) * 128;
        Ap = vbf; Wp = WkvT; bp = bkv; outp = Kb; sc = 1.0f;
        vpath = (n0 >= 1024);
    }

    floatx4 acc[4][4] = {};
    const unsigned short* ga0 = Ap + (size_t)(m0 + lrow) * 1024 + lswz;
    const unsigned short* gb0 = Wp + (size_t)(n0 + lrow) * 1024 + lswz;

    if (!vpath) {
        kloop<1>(ga0, gb0, As, Bs, acc, w, lane);
        // D[row=n][col=m]: lane holds 4 consecutive n at fixed m.
        // Bounce per n-half: Ep[128 m][72 pad] shorts.
        __syncthreads();   // all waves done reading staging LDS
#pragma unroll
        for (int hn = 0; hn < 2; ++hn) {
            if ((w & 1) == hn) {
#pragma unroll
                for (int ni = 0; ni < 4; ++ni) {
                    const int nb = n0 + wc + ni * 16 + quad * 4;
                    const floatx4 b4 = *(const floatx4*)(bp + nb);
#pragma unroll
                    for (int mi = 0; mi < 4; ++mi) {
                        const int ml = wr + mi * 16 + l15;
                        floatx4 v = acc[mi][ni];
                        uintx2 o = { pk2((v[0] + b4[0]) * sc, (v[1] + b4[1]) * sc),
                                     pk2((v[2] + b4[2]) * sc, (v[3] + b4[3]) * sc) };
                        *(uintx2*)(SMEM + ml * 72 + ni * 16 + quad * 4) = o;
                    }
                }
            }
            __syncthreads();
            // 128 rows x 8 chunks of 16B; 8 consecutive threads = 128B segment
#pragma unroll
            for (int p = 0; p < 4; ++p) {
                int u   = p * 256 + t;
                int row = u >> 3, ch = u & 7;
                uintx4 x = *(const uintx4*)(SMEM + row * 72 + ch * 8);
                *(uintx4*)(outp + (size_t)(m0 + row) * 1024 + (n0 & 1023) + hn * 64 + ch * 8) = x;
            }
            __syncthreads();
        }
    } else {
        kloop<0>(ga0, gb0, As, Bs, acc, w, lane);
        // D[row=m][col=n]: lane holds 4 consecutive s at fixed c.
        // Bounce per c-half: Ep[64 c][136 pad] shorts.
        const int c0 = n0 - 1024;
        const int s0 = m0 & 1023;
        const int bb = m0 >> 10;
        __syncthreads();
#pragma unroll
        for (int hc = 0; hc < 2; ++hc) {
            if ((w & 1) == hc) {
#pragma unroll
                for (int ni = 0; ni < 4; ++ni) {
                    const int rl = ni * 16 + l15;            // c within half
                    const float bv = bp[n0 + wc + ni * 16 + l15];
#pragma unroll
                    for (int mi = 0; mi < 4; ++mi) {
                        const int sl = wr + mi * 16 + quad * 4;   // s-local
                        floatx4 v = acc[mi][ni];
                        uintx2 o = { pk2(v[0] + bv, v[1] + bv), pk2(v[2] + bv, v[3] + bv) };
                        *(uintx2*)(SMEM + rl * 136 + sl) = o;
                    }
                }
            }
            __syncthreads();
            // 64 rows x 16 chunks of 16B; 16 consecutive threads = 256B segment
#pragma unroll
            for (int p = 0; p < 4; ++p) {
                int u   = p * 256 + t;
                int row = u >> 4, ch = u & 15;
                uintx4 x = *(const uintx4*)(SMEM + row * 136 + ch * 8);
                *(uintx4*)(Vtg + ((size_t)(bb * 1024 + c0 + hc * 64 + row)) * 1024 + s0 + ch * 8) = x;
            }
            __syncthreads();
        }
    }
}

// ---------------- output projection GEMM: fp32 out, 16B stores (round-4) --------
__global__ __launch_bounds__(256, 4) void o_gemm_k(const unsigned short* __restrict__ Hb,
                                                   const unsigned short* __restrict__ WoT,
                                                   const float* __restrict__ bo,
                                                   float* __restrict__ out) {
    __shared__ unsigned short As[128 * 64];
    __shared__ unsigned short Bs[128 * 64];
    const int t    = threadIdx.x;
    const int lane = t & 63;
    const int w    = t >> 6;
    const int quad = lane >> 4;
    const int l15  = lane & 15;
    const int wr   = (w >> 1) * 64;
    const int wc   = (w & 1) * 64;
    const int lrow = lane >> 3;
    const int lswz = ((lane & 7) ^ lrow) * 8;
    const int m0   = (blockIdx.x & 63) * 128;
    const int n0   = (blockIdx.x >> 6) * 128;

    floatx4 acc[4][4] = {};
    const unsigned short* ga0 = Hb  + (size_t)(m0 + lrow) * 1024 + lswz;
    const unsigned short* gb0 = WoT + (size_t)(n0 + lrow) * 1024 + lswz;
    kloop<1>(ga0, gb0, As, Bs, acc, w, lane);

#pragma unroll
    for (int ni = 0; ni < 4; ++ni) {
        const int nb = n0 + wc + ni * 16 + quad * 4;
        const floatx4 b4 = *(const floatx4*)(bo + nb);
#pragma unroll
        for (int mi = 0; mi < 4; ++mi) {
            const int m = m0 + wr + mi * 16 + l15;
            floatx4 v = acc[mi][ni];
            floatx4 o = { v[0] + b4[0], v[1] + b4[1], v[2] + b4[2], v[3] + b4[3] };
            *(floatx4*)(out + (size_t)m * 1024 + nb) = o;
        }
    }
}

// ---------------- flash attention v5: 256-row Q-tile, 8 waves, 512 threads -------
// (round-5 verified winner, unchanged)
__global__ __launch_bounds__(512, 4) void attn_kernel(const unsigned short* __restrict__ Qb,
                                                      const unsigned short* __restrict__ Kb,
                                                      const unsigned short* __restrict__ Vtg,
                                                      unsigned short* __restrict__ Hb) {
    __shared__ unsigned short QPs[256 * 64];      // 32KB: Q staging, then 8x per-wave P
    __shared__ unsigned short Ks[2][64 * 64];     // [buf][kk][d]  swizzled
    __shared__ unsigned short Vs[2][64 * 64];     // [buf][d][kk]  swizzled

    const int lin = blockIdx.x;                   // 512 blocks
    const int xcd = lin & 7;
    const int grp = lin >> 3;                     // [0,64)
    const int bh  = xcd * 16 + (grp >> 2);        // [0,128)
    const int qt  = grp & 3;
    const int b   = bh >> 4;
    const int h   = bh & 15;
    const int q0  = qt * 256;

    const int t    = threadIdx.x;
    const int lane = t & 63;
    const int w    = t >> 6;                      // [0,8)
    const int quad = lane >> 4;
    const int l15  = lane & 15;
    const int e7   = l15 & 7;
    const int lrow = lane >> 3;
    const int lswz = ((lane & 7) ^ lrow) * 8;

    {
        const unsigned short* gq = Qb + ((size_t)(b * S_ + q0)) * D_ + h * HD_;
#pragma unroll
        for (int i = 0; i < 4; ++i) {
            int r0 = (w * 4 + i) * 8;             // rows [0,256) across 8 waves
            async16(gq + (size_t)(r0 + lrow) * D_ + lswz, QPs + r0 * 64);
        }
    }
    __syncthreads();

    bf16x8 bQ[2][2];
#pragma unroll
    for (int ks = 0; ks < 2; ++ks)
#pragma unroll
        for (int ni = 0; ni < 2; ++ni)
            bQ[ks][ni] = *(const bf16x8*)(QPs + (w * 32 + ni * 16 + l15) * 64 + ((ks * 4 + quad) ^ e7) * 8);

    const unsigned short* gkbase = Kb  + ((size_t)b * S_) * D_ + h * HD_;
    const unsigned short* gvbase = Vtg + ((size_t)(b * D_ + h * HD_)) * S_;

    float   lsum[2] = { 0.f, 0.f };
    floatx4 oacc[4][2] = {};
    unsigned short* Psw = QPs + w * (32 * 64);    // wave-private 4KB region

    auto stageK = [&](int kt, int buf) {
        int r0 = w * 8;                           // each wave stages 8 rows
        async16(gkbase + (size_t)(kt * 64 + r0 + lrow) * D_ + lswz, &Ks[buf][r0 * 64]);
    };
    auto stageV = [&](int kt, int buf) {
        int r0 = w * 8;
        async16(gvbase + (size_t)(r0 + lrow) * S_ + kt * 64 + lswz, &Vs[buf][r0 * 64]);
    };

    // prologue: tile 0 -> buffer 0
    stageK(0, 0);
    stageV(0, 0);

#pragma unroll 1
    for (int kt = 0; kt < 16; ++kt) {
        const int cur = kt & 1;
        asm volatile("s_waitcnt vmcnt(0)\n\ts_barrier" ::: "memory");
        if (kt < 15) { stageK(kt + 1, cur ^ 1); stageV(kt + 1, cur ^ 1); }

        floatx4 st[4][2] = {};
#pragma unroll
        for (int ks = 0; ks < 2; ++ks) {
            bf16x8 aK[4];
#pragma unroll
            for (int mi = 0; mi < 4; ++mi)
                aK[mi] = *(const bf16x8*)(&Ks[cur][0] + (mi * 16 + l15) * 64 + ((ks * 4 + quad) ^ e7) * 8);
            __builtin_amdgcn_s_setprio(1);
#pragma unroll
            for (int mi = 0; mi < 4; ++mi)
#pragma unroll
                for (int ni = 0; ni < 2; ++ni)
                    st[mi][ni] = __builtin_amdgcn_mfma_f32_16x16x32_bf16(aK[mi], bQ[ks][ni], st[mi][ni], 0, 0, 0);
            __builtin_amdgcn_s_setprio(0);
        }

#pragma unroll
        for (int ni = 0; ni < 2; ++ni) {
            float ls = 0.f;
#pragma unroll
            for (int mi = 0; mi < 4; ++mi) {
                float p0 = __builtin_amdgcn_exp2f(st[mi][ni][0]);
                float p1 = __builtin_amdgcn_exp2f(st[mi][ni][1]);
                float p2 = __builtin_amdgcn_exp2f(st[mi][ni][2]);
                float p3 = __builtin_amdgcn_exp2f(st[mi][ni][3]);
                ls += (p0 + p1) + (p2 + p3);
                uintx2 pk = { pk2(p0, p1), pk2(p2, p3) };
                *(uintx2*)(Psw + (ni * 16 + l15) * 64 +
                           (((2 * mi + (quad >> 1)) ^ e7) * 8 + (quad & 1) * 4)) = pk;
            }
            lsum[ni] += ls;
        }

#pragma unroll
        for (int ks = 0; ks < 2; ++ks) {
            bf16x8 aV[4], bP[2];
#pragma unroll
            for (int mi = 0; mi < 4; ++mi)
                aV[mi] = *(const bf16x8*)(&Vs[cur][0] + (mi * 16 + l15) * 64 + ((ks * 4 + quad) ^ e7) * 8);
#pragma unroll
            for (int ni = 0; ni < 2; ++ni)
                bP[ni] = *(const bf16x8*)(Psw + (ni * 16 + l15) * 64 + ((ks * 4 + quad) ^ e7) * 8);
            __builtin_amdgcn_s_setprio(1);
#pragma unroll
            for (int mi = 0; mi < 4; ++mi)
#pragma unroll
                for (int ni = 0; ni < 2; ++ni)
                    oacc[mi][ni] = __builtin_amdgcn_mfma_f32_16x16x32_bf16(aV[mi], bP[ni], oacc[mi][ni], 0, 0, 0);
            __builtin_amdgcn_s_setprio(0);
        }
    }

    float rl[2];
#pragma unroll
    for (int ni = 0; ni < 2; ++ni) {
        float l = lsum[ni];
        l += __shfl_xor(l, 16);
        l += __shfl_xor(l, 32);
        rl[ni] = 1.f / l;
    }
#pragma unroll
    for (int mi = 0; mi < 4; ++mi)
#pragma unroll
        for (int ni = 0; ni < 2; ++ni) {
            uintx2 pk = { pk2(oacc[mi][ni][0] * rl[ni], oacc[mi][ni][1] * rl[ni]),
                          pk2(oacc[mi][ni][2] * rl[ni], oacc[mi][ni][3] * rl[ni]) };
            *(uintx2*)(Psw + (ni * 16 + l15) * 64 +
                       (((2 * mi + (quad >> 1)) ^ e7) * 8 + (quad & 1) * 4)) = pk;
        }
    {
        int qrow = lane >> 1;
        int kh   = lane & 1;
        size_t obase = ((size_t)(b * S_ + q0 + w * 32 + qrow)) * D_ + h * HD_ + kh * 32;
        int e = qrow & 7;
#pragma unroll
        for (int j = 0; j < 4; ++j) {
            int chunk = kh * 4 + j;
            *(uintx4*)(Hb + obase + j * 8) =
                *(const uintx4*)(Psw + qrow * 64 + ((chunk ^ e) * 8));
        }
    }
}

// ---------------- launcher ----------------
extern "C" void kernel_launch(void* const* d_in, const int* in_sizes, int n_in,
                              void* d_out, int out_size, void* d_ws, size_t ws_size,
                              hipStream_t stream) {
    (void)in_sizes; (void)n_in; (void)out_size; (void)ws_size;
    const float* query = (const float*)d_in[0];
    const float* value = (const float*)d_in[1];
    const float* Wq    = (const float*)d_in[2];
    const float* bq    = (const float*)d_in[3];
    const float* Wkv   = (const float*)d_in[4];
    const float* bkv   = (const float*)d_in[5];
    const float* Wo    = (const float*)d_in[6];
    const float* bo    = (const float*)d_in[7];

    const size_t MS = (size_t)B_ * S_;   // 8192
    char* p = (char*)d_ws;               // total 88 MB
    unsigned short* qbf  = (unsigned short*)p; p += MS * D_ * 2;
    unsigned short* vbf  = (unsigned short*)p; p += MS * D_ * 2;
    unsigned short* WqT  = (unsigned short*)p; p += (size_t)D_ * D_ * 2;
    unsigned short* WkvT = (unsigned short*)p; p += (size_t)2 * D_ * D_ * 2;
    unsigned short* WoT  = (unsigned short*)p; p += (size_t)D_ * D_ * 2;
    unsigned short* Qb   = (unsigned short*)p; p += MS * D_ * 2;
    unsigned short* Kb   = (unsigned short*)p; p += MS * D_ * 2;
    unsigned short* Vtg  = (unsigned short*)p; p += MS * D_ * 2;
    unsigned short* Hb   = qbf;   // qbf dead after qkv_gemm; reuse for attn output

    const float cexp = 0.125f * 1.44269504088896341f;   // 1/sqrt(HD) * log2(e)

    prep_k<<<5120, 256, 0, stream>>>(query, value, qbf, vbf, Wq, Wkv, Wo, WqT, WkvT, WoT);
    qkv_gemm_k<<<1536, 256, 0, stream>>>(qbf, vbf, WqT, WkvT, bq, bkv, Qb, Kb, Vtg, cexp);
    attn_kernel<<<512, 512, 0, stream>>>(Qb, Kb, Vtg, Hb);
    o_gemm_k<<<512, 256, 0, stream>>>(Hb, WoT, bo, (float*)d_out);
}

// Round 10
// 253.966 us; speedup vs baseline: 1.0477x; 1.0477x over previous
//
#include <hip/hip_runtime.h>
#include <math.h>

// Problem constants
#define B_  8
#define S_  1024
#define D_  1024
#define H_  16
#define HD_ 64

typedef float          floatx4  __attribute__((ext_vector_type(4)));
typedef __bf16         bf16x8   __attribute__((ext_vector_type(8)));
typedef unsigned int   uintx2   __attribute__((ext_vector_type(2)));
typedef unsigned int   uintx4   __attribute__((ext_vector_type(4)));

__device__ __forceinline__ unsigned short f2bf(float f) {
    union { float f; unsigned u; } v; v.f = f;
    unsigned r = v.u + 0x7FFFu + ((v.u >> 16) & 1u);   // RNE
    return (unsigned short)(r >> 16);
}
__device__ __forceinline__ unsigned pk2(float a, float b) {
    union { __bf16 h[2]; unsigned u; } r;
    r.h[0] = (__bf16)a; r.h[1] = (__bf16)b;
    return r.u;
}
// async global->LDS, 16B per lane; LDS dest = wave-uniform base + lane*16
__device__ __forceinline__ void async16(const void* g, void* l) {
    __builtin_amdgcn_global_load_lds(
        (__attribute__((address_space(1))) void*)g,
        (__attribute__((address_space(3))) void*)l, 16, 0, 0);
}

// ---------------- prep: input casts + all weight transposes, one dispatch ----------
// Cast path: 4 floats/array/thread, 8192 blocks (round-8 measured best; wider
// 8-float variant measured SLOWER -- cast is BW/occupancy-bound, not issue-bound).
__global__ __launch_bounds__(256) void prep_k(const float* __restrict__ query,
                                              const float* __restrict__ value,
                                              unsigned short* __restrict__ qbf,
                                              unsigned short* __restrict__ vbf,
                                              const float* __restrict__ Wq,
                                              const float* __restrict__ Wkv,
                                              const float* __restrict__ Wo,
                                              unsigned short* __restrict__ WqT,
                                              unsigned short* __restrict__ WkvT,
                                              unsigned short* __restrict__ WoT) {
    __shared__ float T[64 * 68];
    const int t   = threadIdx.x;
    const int bid = blockIdx.x;
    if (bid < 8192) {
        int i = bid * 256 + t;
        floatx4 a = ((const floatx4*)query)[i];
        floatx4 b = ((const floatx4*)value)[i];
        uintx2 oa = { pk2(a[0], a[1]), pk2(a[2], a[3]) };
        uintx2 ob = { pk2(b[0], b[1]), pk2(b[2], b[3]) };
        ((uintx2*)qbf)[i] = oa;
        ((uintx2*)vbf)[i] = ob;
        return;
    }
    const int lin = bid - 8192;
    const int z   = lin >> 8;
    const float* W; unsigned short* WT; int Ndim, nbase;
    if (z == 0)      { W = Wq;  WT = WqT;  Ndim = 1024; nbase = 0; }
    else if (z == 3) { W = Wo;  WT = WoT;  Ndim = 1024; nbase = 0; }
    else             { W = Wkv; WT = WkvT; Ndim = 2048; nbase = (z - 1) * 1024; }
    const int n0 = (lin & 15) * 64 + nbase;
    const int k0 = ((lin >> 4) & 15) * 64;
#pragma unroll
    for (int rep = 0; rep < 4; ++rep) {
        int kl = (t >> 4) + rep * 16;
        int ns = (t & 15) * 4;
        *(floatx4*)(T + kl * 68 + ns) = *(const floatx4*)(W + (size_t)(k0 + kl) * Ndim + n0 + ns);
    }
    __syncthreads();
#pragma unroll
    for (int rep = 0; rep < 2; ++rep) {
        int nl = (t >> 3) + rep * 32;
        int ks = (t & 7) * 8;
        union { unsigned short s[8]; uintx4 u; } o;
#pragma unroll
        for (int j = 0; j < 8; ++j) o.s[j] = f2bf(T[(ks + j) * 68 + nl]);
        *(uintx4*)(WT + (size_t)(n0 + nl) * 1024 + k0 + ks) = o.u;
    }
}

// ---------------- shared GEMM K-loop: BK=64, XOR-swizzled LDS (verified) ----------
// LDS tile rows: 64 shorts (128 B = one full bank sweep), logical 8-short chunk c
// of row r stored at position c^(r&7); inverse swizzle applied on global source.
// Fragment reads then alias only 2-way (free). SWAP=1 -> D^T (row=n,col=m).
// ga0/gb0 must already include (+ lrow*1024 + lswz).
template<int SWAP>
__device__ __forceinline__ void kloop(const unsigned short* __restrict__ ga0,
                                      const unsigned short* __restrict__ gb0,
                                      unsigned short* __restrict__ As,
                                      unsigned short* __restrict__ Bs,
                                      floatx4 (&acc)[4][4],
                                      int w, int lane) {
    const int quad = lane >> 4;
    const int l15  = lane & 15;
    const int e7   = l15 & 7;
    const int wr   = (w >> 1) * 64;
    const int wc   = (w & 1) * 64;
    for (int k0 = 0; k0 < 1024; k0 += 64) {
        if (k0) __syncthreads();   // prev-iter LDS reads done before overwrite
#pragma unroll
        for (int i = 0; i < 4; ++i) {
            int c = i * 4 + w;     // rows [c*8, c*8+8)
            async16(ga0 + (size_t)(c * 8) * 1024 + k0, As + c * 512);
            async16(gb0 + (size_t)(c * 8) * 1024 + k0, Bs + c * 512);
        }
        __syncthreads();           // drains vmcnt before fragment reads
#pragma unroll
        for (int ks = 0; ks < 2; ++ks) {
            bf16x8 af[4], bf[4];
#pragma unroll
            for (int mi = 0; mi < 4; ++mi)
                af[mi] = *(const bf16x8*)(As + (wr + mi * 16 + l15) * 64 + (((ks * 4 + quad) ^ e7) * 8));
#pragma unroll
            for (int ni = 0; ni < 4; ++ni)
                bf[ni] = *(const bf16x8*)(Bs + (wc + ni * 16 + l15) * 64 + (((ks * 4 + quad) ^ e7) * 8));
#pragma unroll
            for (int mi = 0; mi < 4; ++mi)
#pragma unroll
                for (int ni = 0; ni < 4; ++ni)
                    acc[mi][ni] = SWAP
                        ? __builtin_amdgcn_mfma_f32_16x16x32_bf16(bf[ni], af[mi], acc[mi][ni], 0, 0, 0)
                        : __builtin_amdgcn_mfma_f32_16x16x32_bf16(af[mi], bf[ni], acc[mi][ni], 0, 0, 0);
        }
    }
}

// ---------------- fused Q + KV projection GEMM (round-4/8 measured best) ----------
// blocks [0,512):    Q:  Qb[m][n]  = (qbf*WqT + bq) * cexp
// blocks [512,1536): KV: n0<1024 -> Kb[m][n]; n0>=1024 -> V: transposed
//                    packed write Vtg[(b*1024+c)][s]
// Epilogue bounces C through the dead staging LDS (16B/lane coalesced stores).
__global__ __launch_bounds__(256, 4) void qkv_gemm_k(const unsigned short* __restrict__ qbf,
                                                     const unsigned short* __restrict__ vbf,
                                                     const unsigned short* __restrict__ WqT,
                                                     const unsigned short* __restrict__ WkvT,
                                                     const float* __restrict__ bq,
                                                     const float* __restrict__ bkv,
                                                     unsigned short* __restrict__ Qb,
                                                     unsigned short* __restrict__ Kb,
                                                     unsigned short* __restrict__ Vtg,
                                                     float cexp) {
    __shared__ unsigned short SMEM[2 * 128 * 64];   // As | Bs; reused by epilogue
    unsigned short* As = SMEM;
    unsigned short* Bs = SMEM + 128 * 64;
    const int t    = threadIdx.x;
    const int lane = t & 63;
    const int w    = t >> 6;
    const int quad = lane >> 4;
    const int l15  = lane & 15;
    const int wr   = (w >> 1) * 64;
    const int wc   = (w & 1) * 64;
    const int lrow = lane >> 3;
    const int lswz = ((lane & 7) ^ lrow) * 8;

    const int bid = blockIdx.x;
    int m0, n0;
    const unsigned short *Ap, *Wp;
    const float* bp;
    unsigned short* outp;
    float sc;
    bool vpath = false;
    if (bid < 512) {
        m0 = (bid & 63) * 128; n0 = (bid >> 6) * 128;
        Ap = qbf; Wp = WqT; bp = bq; outp = Qb; sc = cexp;
    } else {
        int b2 = bid - 512;
        m0 = (b2 & 63) * 128; n0 = (b2 >> 6) * 128;
        Ap = vbf; Wp = WkvT; bp = bkv; outp = Kb; sc = 1.0f;
        vpath = (n0 >= 1024);
    }

    floatx4 acc[4][4] = {};
    const unsigned short* ga0 = Ap + (size_t)(m0 + lrow) * 1024 + lswz;
    const unsigned short* gb0 = Wp + (size_t)(n0 + lrow) * 1024 + lswz;

    if (!vpath) {
        kloop<1>(ga0, gb0, As, Bs, acc, w, lane);
        // D[row=n][col=m]: lane holds 4 consecutive n at fixed m.
        // Bounce per n-half: Ep[128 m][72 pad] shorts.
        __syncthreads();   // all waves done reading staging LDS
#pragma unroll
        for (int hn = 0; hn < 2; ++hn) {
            if ((w & 1) == hn) {
#pragma unroll
                for (int ni = 0; ni < 4; ++ni) {
                    const int nb = n0 + wc + ni * 16 + quad * 4;
                    const floatx4 b4 = *(const floatx4*)(bp + nb);
#pragma unroll
                    for (int mi = 0; mi < 4; ++mi) {
                        const int ml = wr + mi * 16 + l15;
                        floatx4 v = acc[mi][ni];
                        uintx2 o = { pk2((v[0] + b4[0]) * sc, (v[1] + b4[1]) * sc),
                                     pk2((v[2] + b4[2]) * sc, (v[3] + b4[3]) * sc) };
                        *(uintx2*)(SMEM + ml * 72 + ni * 16 + quad * 4) = o;
                    }
                }
            }
            __syncthreads();
            // 128 rows x 8 chunks of 16B; 8 consecutive threads = 128B segment
#pragma unroll
            for (int p = 0; p < 4; ++p) {
                int u   = p * 256 + t;
                int row = u >> 3, ch = u & 7;
                uintx4 x = *(const uintx4*)(SMEM + row * 72 + ch * 8);
                *(uintx4*)(outp + (size_t)(m0 + row) * 1024 + (n0 & 1023) + hn * 64 + ch * 8) = x;
            }
            __syncthreads();
        }
    } else {
        kloop<0>(ga0, gb0, As, Bs, acc, w, lane);
        // D[row=m][col=n]: lane holds 4 consecutive s at fixed c.
        // Bounce per c-half: Ep[64 c][136 pad] shorts.
        const int c0 = n0 - 1024;
        const int s0 = m0 & 1023;
        const int bb = m0 >> 10;
        __syncthreads();
#pragma unroll
        for (int hc = 0; hc < 2; ++hc) {
            if ((w & 1) == hc) {
#pragma unroll
                for (int ni = 0; ni < 4; ++ni) {
                    const int rl = ni * 16 + l15;            // c within half
                    const float bv = bp[n0 + wc + ni * 16 + l15];
#pragma unroll
                    for (int mi = 0; mi < 4; ++mi) {
                        const int sl = wr + mi * 16 + quad * 4;   // s-local
                        floatx4 v = acc[mi][ni];
                        uintx2 o = { pk2(v[0] + bv, v[1] + bv), pk2(v[2] + bv, v[3] + bv) };
                        *(uintx2*)(SMEM + rl * 136 + sl) = o;
                    }
                }
            }
            __syncthreads();
            // 64 rows x 16 chunks of 16B; 16 consecutive threads = 256B segment
#pragma unroll
            for (int p = 0; p < 4; ++p) {
                int u   = p * 256 + t;
                int row = u >> 4, ch = u & 15;
                uintx4 x = *(const uintx4*)(SMEM + row * 136 + ch * 8);
                *(uintx4*)(Vtg + ((size_t)(bb * 1024 + c0 + hc * 64 + row)) * 1024 + s0 + ch * 8) = x;
            }
            __syncthreads();
        }
    }
}

// ---------------- output projection GEMM: fp32 out, 16B stores (round-4) --------
__global__ __launch_bounds__(256, 4) void o_gemm_k(const unsigned short* __restrict__ Hb,
                                                   const unsigned short* __restrict__ WoT,
                                                   const float* __restrict__ bo,
                                                   float* __restrict__ out) {
    __shared__ unsigned short As[128 * 64];
    __shared__ unsigned short Bs[128 * 64];
    const int t    = threadIdx.x;
    const int lane = t & 63;
    const int w    = t >> 6;
    const int quad = lane >> 4;
    const int l15  = lane & 15;
    const int wr   = (w >> 1) * 64;
    const int wc   = (w & 1) * 64;
    const int lrow = lane >> 3;
    const int lswz = ((lane & 7) ^ lrow) * 8;
    const int m0   = (blockIdx.x & 63) * 128;
    const int n0   = (blockIdx.x >> 6) * 128;

    floatx4 acc[4][4] = {};
    const unsigned short* ga0 = Hb  + (size_t)(m0 + lrow) * 1024 + lswz;
    const unsigned short* gb0 = WoT + (size_t)(n0 + lrow) * 1024 + lswz;
    kloop<1>(ga0, gb0, As, Bs, acc, w, lane);

#pragma unroll
    for (int ni = 0; ni < 4; ++ni) {
        const int nb = n0 + wc + ni * 16 + quad * 4;
        const floatx4 b4 = *(const floatx4*)(bo + nb);
#pragma unroll
        for (int mi = 0; mi < 4; ++mi) {
            const int m = m0 + wr + mi * 16 + l15;
            floatx4 v = acc[mi][ni];
            floatx4 o = { v[0] + b4[0], v[1] + b4[1], v[2] + b4[2], v[3] + b4[3] };
            *(floatx4*)(out + (size_t)m * 1024 + nb) = o;
        }
    }
}

// ---------------- flash attention v5: 256-row Q-tile, 8 waves, 512 threads -------
// (round-5 verified winner, unchanged)
__global__ __launch_bounds__(512, 4) void attn_kernel(const unsigned short* __restrict__ Qb,
                                                      const unsigned short* __restrict__ Kb,
                                                      const unsigned short* __restrict__ Vtg,
                                                      unsigned short* __restrict__ Hb) {
    __shared__ unsigned short QPs[256 * 64];      // 32KB: Q staging, then 8x per-wave P
    __shared__ unsigned short Ks[2][64 * 64];     // [buf][kk][d]  swizzled
    __shared__ unsigned short Vs[2][64 * 64];     // [buf][d][kk]  swizzled

    const int lin = blockIdx.x;                   // 512 blocks
    const int xcd = lin & 7;
    const int grp = lin >> 3;                     // [0,64)
    const int bh  = xcd * 16 + (grp >> 2);        // [0,128)
    const int qt  = grp & 3;
    const int b   = bh >> 4;
    const int h   = bh & 15;
    const int q0  = qt * 256;

    const int t    = threadIdx.x;
    const int lane = t & 63;
    const int w    = t >> 6;                      // [0,8)
    const int quad = lane >> 4;
    const int l15  = lane & 15;
    const int e7   = l15 & 7;
    const int lrow = lane >> 3;
    const int lswz = ((lane & 7) ^ lrow) * 8;

    {
        const unsigned short* gq = Qb + ((size_t)(b * S_ + q0)) * D_ + h * HD_;
#pragma unroll
        for (int i = 0; i < 4; ++i) {
            int r0 = (w * 4 + i) * 8;             // rows [0,256) across 8 waves
            async16(gq + (size_t)(r0 + lrow) * D_ + lswz, QPs + r0 * 64);
        }
    }
    __syncthreads();

    bf16x8 bQ[2][2];
#pragma unroll
    for (int ks = 0; ks < 2; ++ks)
#pragma unroll
        for (int ni = 0; ni < 2; ++ni)
            bQ[ks][ni] = *(const bf16x8*)(QPs + (w * 32 + ni * 16 + l15) * 64 + ((ks * 4 + quad) ^ e7) * 8);

    const unsigned short* gkbase = Kb  + ((size_t)b * S_) * D_ + h * HD_;
    const unsigned short* gvbase = Vtg + ((size_t)(b * D_ + h * HD_)) * S_;

    float   lsum[2] = { 0.f, 0.f };
    floatx4 oacc[4][2] = {};
    unsigned short* Psw = QPs + w * (32 * 64);    // wave-private 4KB region

    auto stageK = [&](int kt, int buf) {
        int r0 = w * 8;                           // each wave stages 8 rows
        async16(gkbase + (size_t)(kt * 64 + r0 + lrow) * D_ + lswz, &Ks[buf][r0 * 64]);
    };
    auto stageV = [&](int kt, int buf) {
        int r0 = w * 8;
        async16(gvbase + (size_t)(r0 + lrow) * S_ + kt * 64 + lswz, &Vs[buf][r0 * 64]);
    };

    // prologue: tile 0 -> buffer 0
    stageK(0, 0);
    stageV(0, 0);

#pragma unroll 1
    for (int kt = 0; kt < 16; ++kt) {
        const int cur = kt & 1;
        asm volatile("s_waitcnt vmcnt(0)\n\ts_barrier" ::: "memory");
        if (kt < 15) { stageK(kt + 1, cur ^ 1); stageV(kt + 1, cur ^ 1); }

        floatx4 st[4][2] = {};
#pragma unroll
        for (int ks = 0; ks < 2; ++ks) {
            bf16x8 aK[4];
#pragma unroll
            for (int mi = 0; mi < 4; ++mi)
                aK[mi] = *(const bf16x8*)(&Ks[cur][0] + (mi * 16 + l15) * 64 + ((ks * 4 + quad) ^ e7) * 8);
            __builtin_amdgcn_s_setprio(1);
#pragma unroll
            for (int mi = 0; mi < 4; ++mi)
#pragma unroll
                for (int ni = 0; ni < 2; ++ni)
                    st[mi][ni] = __builtin_amdgcn_mfma_f32_16x16x32_bf16(aK[mi], bQ[ks][ni], st[mi][ni], 0, 0, 0);
            __builtin_amdgcn_s_setprio(0);
        }

#pragma unroll
        for (int ni = 0; ni < 2; ++ni) {
            float ls = 0.f;
#pragma unroll
            for (int mi = 0; mi < 4; ++mi) {
                float p0 = __builtin_amdgcn_exp2f(st[mi][ni][0]);
                float p1 = __builtin_amdgcn_exp2f(st[mi][ni][1]);
                float p2 = __builtin_amdgcn_exp2f(st[mi][ni][2]);
                float p3 = __builtin_amdgcn_exp2f(st[mi][ni][3]);
                ls += (p0 + p1) + (p2 + p3);
                uintx2 pk = { pk2(p0, p1), pk2(p2, p3) };
                *(uintx2*)(Psw + (ni * 16 + l15) * 64 +
                           (((2 * mi + (quad >> 1)) ^ e7) * 8 + (quad & 1) * 4)) = pk;
            }
            lsum[ni] += ls;
        }

#pragma unroll
        for (int ks = 0; ks < 2; ++ks) {
            bf16x8 aV[4], bP[2];
#pragma unroll
            for (int mi = 0; mi < 4; ++mi)
                aV[mi] = *(const bf16x8*)(&Vs[cur][0] + (mi * 16 + l15) * 64 + ((ks * 4 + quad) ^ e7) * 8);
#pragma unroll
            for (int ni = 0; ni < 2; ++ni)
                bP[ni] = *(const bf16x8*)(Psw + (ni * 16 + l15) * 64 + ((ks * 4 + quad) ^ e7) * 8);
            __builtin_amdgcn_s_setprio(1);
#pragma unroll
            for (int mi = 0; mi < 4; ++mi)
#pragma unroll
                for (int ni = 0; ni < 2; ++ni)
                    oacc[mi][ni] = __builtin_amdgcn_mfma_f32_16x16x32_bf16(aV[mi], bP[ni], oacc[mi][ni], 0, 0, 0);
            __builtin_amdgcn_s_setprio(0);
        }
    }

    float rl[2];
#pragma unroll
    for (int ni = 0; ni < 2; ++ni) {
        float l = lsum[ni];
        l += __shfl_xor(l, 16);
        l += __shfl_xor(l, 32);
        rl[ni] = 1.f / l;
    }
#pragma unroll
    for (int mi = 0; mi < 4; ++mi)
#pragma unroll
        for (int ni = 0; ni < 2; ++ni) {
            uintx2 pk = { pk2(oacc[mi][ni][0] * rl[ni], oacc[mi][ni][1] * rl[ni]),
                          pk2(oacc[mi][ni][2] * rl[ni], oacc[mi][ni][3] * rl[ni]) };
            *(uintx2*)(Psw + (ni * 16 + l15) * 64 +
                       (((2 * mi + (quad >> 1)) ^ e7) * 8 + (quad & 1) * 4)) = pk;
        }
    {
        int qrow = lane >> 1;
        int kh   = lane & 1;
        size_t obase = ((size_t)(b * S_ + q0 + w * 32 + qrow)) * D_ + h * HD_ + kh * 32;
        int e = qrow & 7;
#pragma unroll
        for (int j = 0; j < 4; ++j) {
            int chunk = kh * 4 + j;
            *(uintx4*)(Hb + obase + j * 8) =
                *(const uintx4*)(Psw + qrow * 64 + ((chunk ^ e) * 8));
        }
    }
}

// ---------------- launcher ----------------
extern "C" void kernel_launch(void* const* d_in, const int* in_sizes, int n_in,
                              void* d_out, int out_size, void* d_ws, size_t ws_size,
                              hipStream_t stream) {
    (void)in_sizes; (void)n_in; (void)out_size; (void)ws_size;
    const float* query = (const float*)d_in[0];
    const float* value = (const float*)d_in[1];
    const float* Wq    = (const float*)d_in[2];
    const float* bq    = (const float*)d_in[3];
    const float* Wkv   = (const float*)d_in[4];
    const float* bkv   = (const float*)d_in[5];
    const float* Wo    = (const float*)d_in[6];
    const float* bo    = (const float*)d_in[7];

    const size_t MS = (size_t)B_ * S_;   // 8192
    char* p = (char*)d_ws;               // total 88 MB
    unsigned short* qbf  = (unsigned short*)p; p += MS * D_ * 2;
    unsigned short* vbf  = (unsigned short*)p; p += MS * D_ * 2;
    unsigned short* WqT  = (unsigned short*)p; p += (size_t)D_ * D_ * 2;
    unsigned short* WkvT = (unsigned short*)p; p += (size_t)2 * D_ * D_ * 2;
    unsigned short* WoT  = (unsigned short*)p; p += (size_t)D_ * D_ * 2;
    unsigned short* Qb   = (unsigned short*)p; p += MS * D_ * 2;
    unsigned short* Kb   = (unsigned short*)p; p += MS * D_ * 2;
    unsigned short* Vtg  = (unsigned short*)p; p += MS * D_ * 2;
    unsigned short* Hb   = qbf;   // qbf dead after qkv_gemm; reuse for attn output

    const float cexp = 0.125f * 1.44269504088896341f;   // 1/sqrt(HD) * log2(e)

    prep_k<<<9216, 256, 0, stream>>>(query, value, qbf, vbf, Wq, Wkv, Wo, WqT, WkvT, WoT);
    qkv_gemm_k<<<1536, 256, 0, stream>>>(qbf, vbf, WqT, WkvT, bq, bkv, Qb, Kb, Vtg, cexp);
    attn_kernel<<<512, 512, 0, stream>>>(Qb, Kb, Vtg, Hb);
    o_gemm_k<<<512, 256, 0, stream>>>(Hb, WoT, bo, (float*)d_out);
}